// Round 1
// baseline (87.783 us; speedup 1.0000x reference)
//
#include <hip/hip_runtime.h>
#include <cstddef>
#include <cstdint>

typedef __attribute__((ext_vector_type(8))) _Float16 f16x8;
typedef __attribute__((ext_vector_type(4))) float f32x4;

constexpr int S = 128;
constexpr int H = 64;
constexpr int A = 8;
constexpr float GAMMA = 0.98f;
constexpr float EPS_CLIP = 0.1f;

__device__ __forceinline__ float swishf(float x) {
    return x * __builtin_amdgcn_rcpf(1.0f + __expf(-x));
}
__device__ __forceinline__ f32x4 mfmaf(f16x8 a, f16x8 b, f32x4 c) {
    return __builtin_amdgcn_mfma_f32_16x16x32_f16(a, b, c, 0, 0, 0);
}

// One fused kernel. Each wave owns 32 row-indices, processed as 2 chunks of 16
// rows. A chunk's MFMA double-tile is [s rows ; s' rows] of the SAME 16 row
// indices, so v_s, logits and v_sp for a row are produced in the same wave and
// the whole per-row PPO epilogue runs in-kernel (no ws round-trip, no epi
// kernel). Chunk 1's 16 dwordx4 loads are issued while chunk 0 computes
// (sustained MLP); chunk 0's loads overlap weight staging + the barrier.
// A-frag (16x32 f16): lane l holds A[l&15][(l>>4)*8 + j].
// B-frag: lane l holds B[(l>>4)*8 + j][l&15].  C/D: col=lane&15, row=(lane>>4)*4+reg.
__global__ __launch_bounds__(256, 3) void ppo_fused(
    const float* __restrict__ s, const float* __restrict__ sp,
    const float* __restrict__ r, const float* __restrict__ done,
    const float* __restrict__ prob_a, const int* __restrict__ aidx,
    const float* __restrict__ W1, const float* __restrict__ b1,
    const float* __restrict__ W2, const float* __restrict__ b2,
    const float* __restrict__ Wa, const float* __restrict__ ba,
    const float* __restrict__ Wc, const float* __restrict__ bc,
    float* __restrict__ out, float* __restrict__ partial)
{
    __shared__ f16x8 sW1[16][64];                        // 16 KB
    __shared__ f16x8 sW2[8][64];                         //  8 KB
    __shared__ f16x8 sWh[2][64];                         //  2 KB
    __shared__ __align__(16) _Float16 hbuf[4][16 * 72];  //  9 KB
    __shared__ float hs[4][16 * 11];                     //  2.75 KB
    __shared__ float sred[256];                          //  1 KB

    const int tid = threadIdx.x;
    const int w = tid >> 6, l = tid & 63, g = l >> 4, n15 = l & 15;
    const int base = blockIdx.x * 128 + w * 32;

    // ---- chunk-0 loads in flight before / under weight staging ----
    float4 raw[16];
    {
        const float* p0 = s  + (size_t)(base + n15) * S + g * 8;
        const float* p1 = sp + (size_t)(base + n15) * S + g * 8;
        #pragma unroll
        for (int kk = 0; kk < 4; ++kk) {
            raw[kk * 2]         = *reinterpret_cast<const float4*>(p0 + kk * 32);
            raw[kk * 2 + 1]     = *reinterpret_cast<const float4*>(p0 + kk * 32 + 4);
            raw[8 + kk * 2]     = *reinterpret_cast<const float4*>(p1 + kk * 32);
            raw[8 + kk * 2 + 1] = *reinterpret_cast<const float4*>(p1 + kk * 32 + 4);
        }
    }
    float rrv[2], dmv[2], pav[2];
    int actv[2] = {0, 0};
    if (l < 16) {
        const int t = base + l;
        rrv[0] = r[t]; dmv[0] = done[t]; pav[0] = prob_a[t]; actv[0] = aidx[t];
    }

    // ---- pack weight fragments (single fp16 term) ----
    for (int idx = tid; idx < 16 * 64; idx += 256) {
        int f = idx >> 6, ll = idx & 63;
        int nt = f >> 2, kk = f & 3;
        int gg = ll >> 4, col = nt * 16 + (ll & 15);
        f16x8 v;
        #pragma unroll
        for (int j = 0; j < 8; ++j)
            v[j] = (_Float16)W1[(kk * 32 + gg * 8 + j) * H + col];
        sW1[f][ll] = v;
    }
    for (int idx = tid; idx < 8 * 64; idx += 256) {
        int f = idx >> 6, ll = idx & 63;
        int nt = f >> 1, kk = f & 1;
        int gg = ll >> 4, col = nt * 16 + (ll & 15);
        f16x8 v;
        #pragma unroll
        for (int j = 0; j < 8; ++j)
            v[j] = (_Float16)W2[(kk * 32 + gg * 8 + j) * H + col];
        sW2[f][ll] = v;
    }
    for (int idx = tid; idx < 2 * 64; idx += 256) {
        int kk = idx >> 6, ll = idx & 63;
        int gg = ll >> 4, q = ll & 15;
        f16x8 v;
        #pragma unroll
        for (int j = 0; j < 8; ++j) {
            int k = kk * 32 + gg * 8 + j;
            v[j] = (_Float16)((q == 0) ? Wc[k] : ((q <= 8) ? Wa[k * A + (q - 1)] : 0.0f));
        }
        sWh[kk][ll] = v;
    }
    __syncthreads();

    float b1r[4], b2r[4];
    #pragma unroll
    for (int nt = 0; nt < 4; ++nt) { b1r[nt] = b1[nt * 16 + n15]; b2r[nt] = b2[nt * 16 + n15]; }
    const float bhr = (n15 == 0) ? bc[0] : ((n15 <= 8) ? ba[n15 - 1] : 0.0f);

    _Float16* hb = hbuf[w];
    float* hsw = hs[w];
    float hacc = 0.f;

    #pragma unroll
    for (int c = 0; c < 2; ++c) {
        const int t0 = base + c * 16;

        // ---- raw -> fp16 A-frags (first use of this chunk's loads) ----
        f16x8 ax[2][4];
        #pragma unroll
        for (int tile = 0; tile < 2; ++tile)
            #pragma unroll
            for (int kk = 0; kk < 4; ++kk) {
                float4 v0 = raw[tile * 8 + kk * 2];
                float4 v1 = raw[tile * 8 + kk * 2 + 1];
                f16x8 a;
                a[0] = (_Float16)v0.x; a[1] = (_Float16)v0.y;
                a[2] = (_Float16)v0.z; a[3] = (_Float16)v0.w;
                a[4] = (_Float16)v1.x; a[5] = (_Float16)v1.y;
                a[6] = (_Float16)v1.z; a[7] = (_Float16)v1.w;
                ax[tile][kk] = a;
            }

        // ---- issue chunk-1 loads: in flight through all of chunk 0 compute ----
        if (c == 0) {
            const float* p0 = s  + (size_t)(base + 16 + n15) * S + g * 8;
            const float* p1 = sp + (size_t)(base + 16 + n15) * S + g * 8;
            #pragma unroll
            for (int kk = 0; kk < 4; ++kk) {
                raw[kk * 2]         = *reinterpret_cast<const float4*>(p0 + kk * 32);
                raw[kk * 2 + 1]     = *reinterpret_cast<const float4*>(p0 + kk * 32 + 4);
                raw[8 + kk * 2]     = *reinterpret_cast<const float4*>(p1 + kk * 32);
                raw[8 + kk * 2 + 1] = *reinterpret_cast<const float4*>(p1 + kk * 32 + 4);
            }
            if (l < 16) {
                const int t = base + 16 + l;
                rrv[1] = r[t]; dmv[1] = done[t]; pav[1] = prob_a[t]; actv[1] = aidx[t];
            }
        }

        // ---- layer 1: [16x128]@[128x64], both tiles share each W-frag read ----
        f32x4 acc[2][4];
        #pragma unroll
        for (int tile = 0; tile < 2; ++tile)
            #pragma unroll
            for (int nt = 0; nt < 4; ++nt)
                acc[tile][nt] = (f32x4){b1r[nt], b1r[nt], b1r[nt], b1r[nt]};
        #pragma unroll
        for (int nt = 0; nt < 4; ++nt)
            #pragma unroll
            for (int kk = 0; kk < 4; ++kk) {
                f16x8 bw = sW1[nt * 4 + kk][l];
                acc[0][nt] = mfmaf(ax[0][kk], bw, acc[0][nt]);
                acc[1][nt] = mfmaf(ax[1][kk], bw, acc[1][nt]);
            }

        // ---- swish + LDS transpose (C layout -> A layout), per tile ----
        f16x8 a2[2][2];
        #pragma unroll
        for (int tile = 0; tile < 2; ++tile) {
            #pragma unroll
            for (int nt = 0; nt < 4; ++nt)
                #pragma unroll
                for (int rj = 0; rj < 4; ++rj)
                    hb[(g * 4 + rj) * 72 + nt * 16 + n15] =
                        (_Float16)swishf(acc[tile][nt][rj]);
            #pragma unroll
            for (int kk = 0; kk < 2; ++kk)
                a2[tile][kk] = *reinterpret_cast<f16x8*>(&hb[n15 * 72 + kk * 32 + g * 8]);
        }

        // ---- layer 2: [16x64]@[64x64] ----
        f32x4 acc2[2][4];
        #pragma unroll
        for (int tile = 0; tile < 2; ++tile)
            #pragma unroll
            for (int nt = 0; nt < 4; ++nt)
                acc2[tile][nt] = (f32x4){b2r[nt], b2r[nt], b2r[nt], b2r[nt]};
        #pragma unroll
        for (int nt = 0; nt < 4; ++nt)
            #pragma unroll
            for (int kk = 0; kk < 2; ++kk) {
                f16x8 bw = sW2[nt * 2 + kk][l];
                acc2[0][nt] = mfmaf(a2[0][kk], bw, acc2[0][nt]);
                acc2[1][nt] = mfmaf(a2[1][kk], bw, acc2[1][nt]);
            }

        // ---- transpose again -> head A-frags ----
        f16x8 a3[2][2];
        #pragma unroll
        for (int tile = 0; tile < 2; ++tile) {
            #pragma unroll
            for (int nt = 0; nt < 4; ++nt)
                #pragma unroll
                for (int rj = 0; rj < 4; ++rj)
                    hb[(g * 4 + rj) * 72 + nt * 16 + n15] =
                        (_Float16)swishf(acc2[tile][nt][rj]);
            #pragma unroll
            for (int kk = 0; kk < 2; ++kk)
                a3[tile][kk] = *reinterpret_cast<f16x8*>(&hb[n15 * 72 + kk * 32 + g * 8]);
        }

        // ---- head: [16x64]@[64x16] (col0=v, col1..8=logits) ----
        f32x4 ah[2] = {(f32x4){bhr, bhr, bhr, bhr}, (f32x4){bhr, bhr, bhr, bhr}};
        #pragma unroll
        for (int kk = 0; kk < 2; ++kk) {
            f16x8 bw = sWh[kk][l];
            ah[0] = mfmaf(a3[0][kk], bw, ah[0]);
            ah[1] = mfmaf(a3[1][kk], bw, ah[1]);
        }

        // tile0 = s rows: stash v + logits (cols 0..8). tile1 = s' rows: v_sp (col 9).
        #pragma unroll
        for (int rj = 0; rj < 4; ++rj) {
            if (n15 <= 8) hsw[(g * 4 + rj) * 11 + n15] = ah[0][rj];
            if (n15 == 0) hsw[(g * 4 + rj) * 11 + 9]  = ah[1][rj];
        }

        // ---- per-row PPO epilogue on lanes 0..15 ----
        if (l < 16) {
            float vs = hsw[l * 11 + 0];
            float lgq[A];
            float m = -1e30f;
            #pragma unroll
            for (int q = 0; q < A; ++q) {
                lgq[q] = hsw[l * 11 + 1 + q];
                m = fmaxf(m, lgq[q]);
            }
            float den = 0.f, num = 0.f;
            #pragma unroll
            for (int q = 0; q < A; ++q) {
                float e = __expf(lgq[q] - m);
                den += e;
                num = (q == actv[c]) ? e : num;
            }
            float pia = num / den;
            float vsp = hsw[l * 11 + 9];

            float ratio = pia / pav[c];
            float td    = fmaf(GAMMA * dmv[c], vsp, rrv[c]);
            float dlt   = rrv[c] + GAMMA * vsp - vs;
            float s1 = ratio * dlt;
            float rcl = fminf(fmaxf(ratio, 1.0f - EPS_CLIP), 1.0f + EPS_CLIP);
            float s2 = rcl * dlt;
            out[t0 + l] = -fminf(s1, s2);

            float err = td - vs;
            float ae = fabsf(err);
            hacc += (ae <= 1.0f) ? (0.5f * err * err) : (ae - 0.5f);
        }
    }

    // ---- block-level huber partial ----
    sred[tid] = hacc;
    __syncthreads();
    #pragma unroll
    for (int off = 128; off > 0; off >>= 1) {
        if (tid < off) sred[tid] += sred[tid + off];
        __syncthreads();
    }
    if (tid == 0) partial[blockIdx.x] = sred[0];
}

// Every block reduces the (small, L2/L3-resident) partial array to the huber
// mean, then adds it to its own slice of out. Replaces reduce+add launches.
__global__ __launch_bounds__(256) void ppo_finish(
    const float* __restrict__ partial, int nparts, float invT,
    float4* __restrict__ out4, int n4)
{
    __shared__ float sred[256];
    const int tid = threadIdx.x;
    float v = 0.f;
    for (int i = tid; i < nparts; i += 256) v += partial[i];
    sred[tid] = v;
    __syncthreads();
    #pragma unroll
    for (int off = 128; off > 0; off >>= 1) {
        if (tid < off) sred[tid] += sred[tid + off];
        __syncthreads();
    }
    const float m = sred[0] * invT;
    const int i = blockIdx.x * 256 + tid;
    if (i < n4) {
        float4 o = out4[i];
        o.x += m; o.y += m; o.z += m; o.w += m;
        out4[i] = o;
    }
}

extern "C" void kernel_launch(void* const* d_in, const int* in_sizes, int n_in,
                              void* d_out, int out_size, void* d_ws, size_t ws_size,
                              hipStream_t stream)
{
    const float* s      = (const float*)d_in[0];
    const float* sp     = (const float*)d_in[1];
    const float* r      = (const float*)d_in[2];
    const float* done   = (const float*)d_in[3];
    const float* prob_a = (const float*)d_in[4];
    const int*   a      = (const int*)d_in[5];
    const float* W1     = (const float*)d_in[6];
    const float* b1     = (const float*)d_in[7];
    const float* W2     = (const float*)d_in[8];
    const float* b2     = (const float*)d_in[9];
    const float* Wa     = (const float*)d_in[10];
    const float* ba     = (const float*)d_in[11];
    const float* Wc     = (const float*)d_in[12];
    const float* bc     = (const float*)d_in[13];

    float* out = (float*)d_out;
    float* partial = (float*)d_ws;

    const int Ttot = in_sizes[0] / S;              // 262144
    const int nb2  = Ttot / 128;                   // 2048 blocks, 128 rows each

    ppo_fused<<<nb2, 256, 0, stream>>>(s, sp, r, done, prob_a, a,
                                       W1, b1, W2, b2, Wa, ba, Wc, bc,
                                       out, partial);

    const int n4 = Ttot / 4;
    ppo_finish<<<(n4 + 255) / 256, 256, 0, stream>>>(partial, nb2,
                                                     1.0f / (float)Ttot,
                                                     (float4*)out, n4);
}

// Round 2
// 75.107 us; speedup vs baseline: 1.1688x; 1.1688x over previous
//
#include <hip/hip_runtime.h>
#include <cstddef>
#include <cstdint>

typedef __attribute__((ext_vector_type(8))) _Float16 f16x8;
typedef __attribute__((ext_vector_type(4))) float f32x4;

constexpr int S = 128;
constexpr int H = 64;
constexpr int A = 8;
constexpr float GAMMA = 0.98f;
constexpr float EPS_CLIP = 0.1f;

__device__ __forceinline__ float swishf(float x) {
    return x * __builtin_amdgcn_rcpf(1.0f + __expf(-x));
}
__device__ __forceinline__ f32x4 mfmaf(f16x8 a, f16x8 b, f32x4 c) {
    return __builtin_amdgcn_mfma_f32_16x16x32_f16(a, b, c, 0, 0, 0);
}

// Grid = 2*nb blocks of 256 threads (4 waves). Blocks [0,nb): pass 0 over s
// (writes v_s and pi_a). Blocks [nb,2nb): pass 1 over s' (writes v_sp).
// Each wave owns 64 rows as 2 double-tiles of 32 rows; both 16-row tiles of a
// double-tile share every weight-fragment ds_read.
// Latency plan: double-tile 0's 16 dwordx4 are issued BEFORE weight staging
// (hidden under staging); double-tile 1's are issued right after double-tile
// 0's cvt (hidden under its MFMA chain). asm memory fences pin the issue
// points so the compiler cannot sink the loads (round-1 failure mode).
// __launch_bounds__(256,3): VGPR budget ~168 so the 16 in-flight float4 stay
// in registers. LDS 38.9 KB; achieved occupancy was ~3 blocks/CU regardless.
// A-frag (16x32 f16): lane l holds A[l&15][(l>>4)*8 + j].
// B-frag: lane l holds B[(l>>4)*8 + j][l&15].  C/D: col=lane&15, row=(lane>>4)*4+reg.
__global__ __launch_bounds__(256, 3) void ppo_fwd(
    const float* __restrict__ s, const float* __restrict__ sp,
    const int* __restrict__ aidx,
    const float* __restrict__ W1, const float* __restrict__ b1,
    const float* __restrict__ W2, const float* __restrict__ b2,
    const float* __restrict__ Wa, const float* __restrict__ ba,
    const float* __restrict__ Wc, const float* __restrict__ bc,
    float* __restrict__ ws_vs, float* __restrict__ ws_pia,
    float* __restrict__ ws_vsp, int nb)
{
    __shared__ f16x8 sW1[16][64];                        // 16 KB
    __shared__ f16x8 sW2[8][64];                         //  8 KB
    __shared__ f16x8 sWh[2][64];                         //  2 KB
    __shared__ __align__(16) _Float16 hbuf[4][16 * 72];  //  9 KB
    __shared__ float hs[4][16 * 11];                     //  2.75 KB

    const int tid = threadIdx.x;
    const int pass = (blockIdx.x >= (unsigned)nb) ? 1 : 0;
    const int rb = blockIdx.x - pass * nb;
    const float* __restrict__ x = pass ? sp : s;

    const int w = tid >> 6, l = tid & 63, g = l >> 4, n15 = l & 15;
    const int wbase = rb * 256 + w * 64;

    // ---- issue double-tile 0 loads + scalars BEFORE staging ----
    float4 raw[16];
    {
        const float* p0 = x + (size_t)(wbase + n15) * S + g * 8;        // tile 0
        const float* p1 = x + (size_t)(wbase + 16 + n15) * S + g * 8;   // tile 1
        #pragma unroll
        for (int kk = 0; kk < 4; ++kk) {
            raw[kk * 2]         = *reinterpret_cast<const float4*>(p0 + kk * 32);
            raw[kk * 2 + 1]     = *reinterpret_cast<const float4*>(p0 + kk * 32 + 4);
            raw[8 + kk * 2]     = *reinterpret_cast<const float4*>(p1 + kk * 32);
            raw[8 + kk * 2 + 1] = *reinterpret_cast<const float4*>(p1 + kk * 32 + 4);
        }
    }
    float b1r[4], b2r[4];
    #pragma unroll
    for (int nt = 0; nt < 4; ++nt) { b1r[nt] = b1[nt * 16 + n15]; b2r[nt] = b2[nt * 16 + n15]; }
    const float bhr = (n15 == 0) ? bc[0] : ((n15 <= 8) ? ba[n15 - 1] : 0.0f);
    int act[2][2] = {{0, 0}, {0, 0}};
    if (pass == 0 && l < 16) {
        #pragma unroll
        for (int mt2 = 0; mt2 < 2; ++mt2) {
            act[mt2][0] = aidx[wbase + mt2 * 32 + l];
            act[mt2][1] = aidx[wbase + mt2 * 32 + 16 + l];
        }
    }
    asm volatile("" ::: "memory");   // pin: x-loads issued before staging

    // ---- pack weight fragments (single fp16 term) ----
    for (int idx = tid; idx < 16 * 64; idx += 256) {
        int f = idx >> 6, ll = idx & 63;
        int nt = f >> 2, kk = f & 3;
        int gg = ll >> 4, col = nt * 16 + (ll & 15);
        f16x8 v;
        #pragma unroll
        for (int j = 0; j < 8; ++j)
            v[j] = (_Float16)W1[(kk * 32 + gg * 8 + j) * H + col];
        sW1[f][ll] = v;
    }
    for (int idx = tid; idx < 8 * 64; idx += 256) {
        int f = idx >> 6, ll = idx & 63;
        int nt = f >> 1, kk = f & 1;
        int gg = ll >> 4, col = nt * 16 + (ll & 15);
        f16x8 v;
        #pragma unroll
        for (int j = 0; j < 8; ++j)
            v[j] = (_Float16)W2[(kk * 32 + gg * 8 + j) * H + col];
        sW2[f][ll] = v;
    }
    for (int idx = tid; idx < 2 * 64; idx += 256) {
        int kk = idx >> 6, ll = idx & 63;
        int gg = ll >> 4, q = ll & 15;
        f16x8 v;
        #pragma unroll
        for (int j = 0; j < 8; ++j) {
            int k = kk * 32 + gg * 8 + j;
            v[j] = (_Float16)((q == 0) ? Wc[k] : ((q <= 8) ? Wa[k * A + (q - 1)] : 0.0f));
        }
        sWh[kk][ll] = v;
    }
    __syncthreads();

    _Float16* hb = hbuf[w];
    float* hsw = hs[w];

    #pragma unroll
    for (int mt2 = 0; mt2 < 2; ++mt2) {
        const int t0 = wbase + mt2 * 32;

        // ---- raw -> fp16 A-frags (first wait on this double-tile's loads) ----
        f16x8 ax[2][4];   // [tile][kk]
        #pragma unroll
        for (int tile = 0; tile < 2; ++tile)
            #pragma unroll
            for (int kk = 0; kk < 4; ++kk) {
                float4 v0 = raw[tile * 8 + kk * 2];
                float4 v1 = raw[tile * 8 + kk * 2 + 1];
                f16x8 a;
                a[0] = (_Float16)v0.x; a[1] = (_Float16)v0.y;
                a[2] = (_Float16)v0.z; a[3] = (_Float16)v0.w;
                a[4] = (_Float16)v1.x; a[5] = (_Float16)v1.y;
                a[6] = (_Float16)v1.z; a[7] = (_Float16)v1.w;
                ax[tile][kk] = a;
            }

        // ---- issue double-tile 1 loads: in flight through this tile's MFMAs ----
        if (mt2 == 0) {
            const float* p0 = x + (size_t)(wbase + 32 + n15) * S + g * 8;
            const float* p1 = x + (size_t)(wbase + 48 + n15) * S + g * 8;
            #pragma unroll
            for (int kk = 0; kk < 4; ++kk) {
                raw[kk * 2]         = *reinterpret_cast<const float4*>(p0 + kk * 32);
                raw[kk * 2 + 1]     = *reinterpret_cast<const float4*>(p0 + kk * 32 + 4);
                raw[8 + kk * 2]     = *reinterpret_cast<const float4*>(p1 + kk * 32);
                raw[8 + kk * 2 + 1] = *reinterpret_cast<const float4*>(p1 + kk * 32 + 4);
            }
            asm volatile("" ::: "memory");   // pin: prefetch issued here
        }

        // ---- layer 1: [16x128]@[128x64], both tiles share each W-frag read ----
        f32x4 acc[2][4];
        #pragma unroll
        for (int tile = 0; tile < 2; ++tile)
            #pragma unroll
            for (int nt = 0; nt < 4; ++nt)
                acc[tile][nt] = (f32x4){b1r[nt], b1r[nt], b1r[nt], b1r[nt]};
        #pragma unroll
        for (int nt = 0; nt < 4; ++nt)
            #pragma unroll
            for (int kk = 0; kk < 4; ++kk) {
                f16x8 bw = sW1[nt * 4 + kk][l];
                acc[0][nt] = mfmaf(ax[0][kk], bw, acc[0][nt]);
                acc[1][nt] = mfmaf(ax[1][kk], bw, acc[1][nt]);
            }

        // ---- swish + LDS transpose (C layout -> A layout), per tile ----
        f16x8 a2[2][2];
        #pragma unroll
        for (int tile = 0; tile < 2; ++tile) {
            #pragma unroll
            for (int nt = 0; nt < 4; ++nt)
                #pragma unroll
                for (int rj = 0; rj < 4; ++rj)
                    hb[(g * 4 + rj) * 72 + nt * 16 + n15] =
                        (_Float16)swishf(acc[tile][nt][rj]);
            #pragma unroll
            for (int kk = 0; kk < 2; ++kk)
                a2[tile][kk] = *reinterpret_cast<f16x8*>(&hb[n15 * 72 + kk * 32 + g * 8]);
        }

        // ---- layer 2: [16x64]@[64x64] ----
        f32x4 acc2[2][4];
        #pragma unroll
        for (int tile = 0; tile < 2; ++tile)
            #pragma unroll
            for (int nt = 0; nt < 4; ++nt)
                acc2[tile][nt] = (f32x4){b2r[nt], b2r[nt], b2r[nt], b2r[nt]};
        #pragma unroll
        for (int nt = 0; nt < 4; ++nt)
            #pragma unroll
            for (int kk = 0; kk < 2; ++kk) {
                f16x8 bw = sW2[nt * 2 + kk][l];
                acc2[0][nt] = mfmaf(a2[0][kk], bw, acc2[0][nt]);
                acc2[1][nt] = mfmaf(a2[1][kk], bw, acc2[1][nt]);
            }

        // ---- transpose again -> head A-frags ----
        f16x8 a3[2][2];
        #pragma unroll
        for (int tile = 0; tile < 2; ++tile) {
            #pragma unroll
            for (int nt = 0; nt < 4; ++nt)
                #pragma unroll
                for (int rj = 0; rj < 4; ++rj)
                    hb[(g * 4 + rj) * 72 + nt * 16 + n15] =
                        (_Float16)swishf(acc2[tile][nt][rj]);
            #pragma unroll
            for (int kk = 0; kk < 2; ++kk)
                a3[tile][kk] = *reinterpret_cast<f16x8*>(&hb[n15 * 72 + kk * 32 + g * 8]);
        }

        // ---- head: [16x64]@[64x16] (col0=v, col1..8=logits) ----
        f32x4 ah[2] = {(f32x4){bhr, bhr, bhr, bhr}, (f32x4){bhr, bhr, bhr, bhr}};
        #pragma unroll
        for (int kk = 0; kk < 2; ++kk) {
            f16x8 bw = sWh[kk][l];
            ah[0] = mfmaf(a3[0][kk], bw, ah[0]);
            ah[1] = mfmaf(a3[1][kk], bw, ah[1]);
        }

        if (pass == 1) {
            // v_sp lives in col 0 = lanes with n15==0; rows g*4+rj
            #pragma unroll
            for (int tile = 0; tile < 2; ++tile)
                if (n15 == 0) {
                    #pragma unroll
                    for (int rj = 0; rj < 4; ++rj)
                        ws_vsp[t0 + tile * 16 + g * 4 + rj] = ah[tile][rj];
                }
        } else {
            // stash v + logits, softmax on lanes 0..15
            #pragma unroll
            for (int tile = 0; tile < 2; ++tile) {
                if (n15 <= 8) {
                    #pragma unroll
                    for (int rj = 0; rj < 4; ++rj)
                        hsw[(g * 4 + rj) * 11 + n15] = ah[tile][rj];
                }
                if (l < 16) {
                    float vs = hsw[l * 11 + 0];
                    float lgq[A];
                    float m = -1e30f;
                    #pragma unroll
                    for (int q = 0; q < A; ++q) {
                        lgq[q] = hsw[l * 11 + 1 + q];
                        m = fmaxf(m, lgq[q]);
                    }
                    float den = 0.f, num = 0.f;
                    #pragma unroll
                    for (int q = 0; q < A; ++q) {
                        float e = __expf(lgq[q] - m);
                        den += e;
                        num = (q == act[mt2][tile]) ? e : num;
                    }
                    int t = t0 + tile * 16 + l;
                    ws_vs[t]  = vs;
                    ws_pia[t] = num / den;
                }
            }
        }
    }
}

// Per-row epilogue: out[t] = -min(surr1,surr2); huber partials per block.
__global__ __launch_bounds__(256) void ppo_epi(
    const float* __restrict__ r, const float* __restrict__ done,
    const float* __restrict__ prob_a,
    const float* __restrict__ ws_vs, const float* __restrict__ ws_pia,
    const float* __restrict__ ws_vsp,
    float* __restrict__ out, float* __restrict__ partial, int Ttot)
{
    __shared__ float sred[256];
    const int tid = threadIdx.x;
    const int t = blockIdx.x * 256 + tid;

    float he = 0.f;
    if (t < Ttot) {
        float vs  = ws_vs[t];
        float vsp = ws_vsp[t];
        float rr  = r[t];
        float dm  = done[t];
        float ratio = ws_pia[t] / prob_a[t];

        float td_target = fmaf(GAMMA * dm, vsp, rr);
        float delta     = rr + GAMMA * vsp - vs;
        float s1 = ratio * delta;
        float rcl = fminf(fmaxf(ratio, 1.0f - EPS_CLIP), 1.0f + EPS_CLIP);
        float s2 = rcl * delta;
        out[t] = -fminf(s1, s2);

        float err = td_target - vs;
        float ae = fabsf(err);
        he = (ae <= 1.0f) ? (0.5f * err * err) : (ae - 0.5f);
    }

    sred[tid] = he;
    __syncthreads();
    #pragma unroll
    for (int off = 128; off > 0; off >>= 1) {
        if (tid < off) sred[tid] += sred[tid + off];
        __syncthreads();
    }
    if (tid == 0) partial[blockIdx.x] = sred[0];
}

// Every block reduces the (L2-resident) partial array to the huber mean, then
// adds it to its own slice of out. Replaces the reduce+add launch pair.
__global__ __launch_bounds__(256) void ppo_finish(
    const float* __restrict__ partial, int nparts, float invT,
    float4* __restrict__ out4, int n4)
{
    __shared__ float sred[256];
    const int tid = threadIdx.x;
    float v = 0.f;
    for (int i = tid; i < nparts; i += 256) v += partial[i];
    sred[tid] = v;
    __syncthreads();
    #pragma unroll
    for (int off = 128; off > 0; off >>= 1) {
        if (tid < off) sred[tid] += sred[tid + off];
        __syncthreads();
    }
    const float m = sred[0] * invT;
    const int i = blockIdx.x * 256 + tid;
    if (i < n4) {
        float4 o = out4[i];
        o.x += m; o.y += m; o.z += m; o.w += m;
        out4[i] = o;
    }
}

extern "C" void kernel_launch(void* const* d_in, const int* in_sizes, int n_in,
                              void* d_out, int out_size, void* d_ws, size_t ws_size,
                              hipStream_t stream)
{
    const float* s      = (const float*)d_in[0];
    const float* sp     = (const float*)d_in[1];
    const float* r      = (const float*)d_in[2];
    const float* done   = (const float*)d_in[3];
    const float* prob_a = (const float*)d_in[4];
    const int*   a      = (const int*)d_in[5];
    const float* W1     = (const float*)d_in[6];
    const float* b1     = (const float*)d_in[7];
    const float* W2     = (const float*)d_in[8];
    const float* b2     = (const float*)d_in[9];
    const float* Wa     = (const float*)d_in[10];
    const float* ba     = (const float*)d_in[11];
    const float* Wc     = (const float*)d_in[12];
    const float* bc     = (const float*)d_in[13];

    float* out = (float*)d_out;
    float* ws  = (float*)d_ws;

    const int Ttot = in_sizes[0] / S;              // 262144
    const int nb   = Ttot / 256;                   // 1024 row-blocks

    float* ws_vs  = ws;
    float* ws_pia = ws + Ttot;
    float* ws_vsp = ws + 2 * (size_t)Ttot;
    float* partial = ws + 3 * (size_t)Ttot;        // nb floats

    ppo_fwd<<<2 * nb, 256, 0, stream>>>(s, sp, a, W1, b1, W2, b2, Wa, ba, Wc, bc,
                                        ws_vs, ws_pia, ws_vsp, nb);
    ppo_epi<<<nb, 256, 0, stream>>>(r, done, prob_a, ws_vs, ws_pia, ws_vsp,
                                    out, partial, Ttot);

    const int n4 = Ttot / 4;
    ppo_finish<<<(n4 + 255) / 256, 256, 0, stream>>>(partial, nb,
                                                     1.0f / (float)Ttot,
                                                     (float4*)out, n4);
}